// Round 2
// baseline (503.461 us; speedup 1.0000x reference)
//
#include <hip/hip_runtime.h>

#define BB 32
#define NN 300
#define HH 1024
#define WW 1024
#define RSTRIP 8                 // rows per block strip
#define NSTRIP (HH / RSTRIP)     // 128 strips per batch
#define SSTRIDE (BB * NN)        // 9600 floats per strip-slice

// One block per (batch, 8-row strip); 512 threads = 8 waves, one row per wave.
//
// v3: COALESCED LOADS. v2's layout gave each lane 16 consecutive floats, so
// every global_load_dwordx4 had lane i at base+i*64B -- 64 cache lines per
// instruction, 25% used each, refetched as L1/L2 thrash (per-CU burst
// footprint 128 KiB vs 32 KiB L1) => ~4x HBM over-fetch, strip ~245 us at
// 1.05 TB/s. Now the 1024-float row is scanned as 4 chunks of 256: lane i
// owns floats [c*256+4i, +4). Every load is a contiguous 1 KiB wave
// transaction. Scan = per-chunk {lane-serial 4 + wave shfl-scan + carry}.
// LDS writes land 8 dwords/bank/instr = conflict-free minimum.
// __launch_bounds__(512,8): cap 64 VGPR -> 4 blocks/CU = 32 waves/CU (full).
__global__ __launch_bounds__(512, 8) void strip_kernel(
    const float* __restrict__ seg,
    const float4* __restrict__ boxes,
    const float* __restrict__ conf,
    float* __restrict__ boxacc)
{
    int blk  = blockIdx.x;
    int b    = blk >> 7;          // / NSTRIP
    int s    = blk & (NSTRIP - 1);
    int r0   = s * RSTRIP;
    int t    = threadIdx.x;
    int lane = t & 63;
    int warp = t >> 6;            // 0..7 -> row within strip

    __shared__ float L[RSTRIP][WW];

    const float* p1 = seg + ((size_t)b * 3 + 1) * ((size_t)HH * WW)
                          + (size_t)(r0 + warp) * WW;
    const float* p2 = p1 + (size_t)HH * WW;   // class 2 plane, same row

    // Box metadata load issued early to overlap with the streaming loads.
    bool hasbox = t < NN;
    float4 bx = make_float4(0.f, 0.f, 0.f, 0.f);
    float cf = 0.f;
    if (hasbox) { bx = boxes[b * NN + t]; cf = conf[b * NN + t]; }

    // Issue all 8 coalesced loads up front (max memory-level parallelism).
    float4 u[4], v[4];
    #pragma unroll
    for (int c = 0; c < 4; ++c) {
        u[c] = *(const float4*)(p2 + c * 256 + lane * 4);
        v[c] = *(const float4*)(p1 + c * 256 + lane * 4);
    }

    // 4 chained {serial-4, wave-scan, carry} passes build the row prefix.
    float carry = 0.f;
    #pragma unroll
    for (int c = 0; c < 4; ++c) {
        float g0 = u[c].x - v[c].x;
        float g1 = u[c].y - v[c].y;
        float g2 = u[c].z - v[c].z;
        float g3 = u[c].w - v[c].w;
        g1 += g0; g2 += g1; g3 += g2;          // inclusive within lane
        float tot  = g3;
        float incl = tot;
        #pragma unroll
        for (int d = 1; d < 64; d <<= 1) {     // wave inclusive scan of totals
            float x = __shfl_up(incl, d, 64);
            if (lane >= d) incl += x;
        }
        float base = carry + (incl - tot);     // exclusive-before-this-lane
        carry += __shfl(incl, 63, 64);         // chunk total -> next chunk
        *(float4*)(&L[warp][c * 256 + lane * 4]) =
            make_float4(g0 + base, g1 + base, g2 + base, g3 + base);
    }
    __syncthreads();

    // Box phase: one box per thread (300 < 512). Unconditional store of the
    // partial (0 if invalid / no overlap) -- no atomics, no boxacc memset.
    if (hasbox) {
        float sum = 0.f;
        float x1f = (bx.x - 0.5f * bx.z) * (float)WW;
        float x2f = (bx.x + 0.5f * bx.z) * (float)WW;
        float y1f = (bx.y - 0.5f * bx.w) * (float)HH;
        float y2f = (bx.y + 0.5f * bx.w) * (float)HH;
        int x1 = min(max((int)truncf(x1f), 0), WW - 1);
        int x2 = min(max((int)truncf(x2f), 0), WW - 1);
        int y1 = min(max((int)truncf(y1f), 0), HH - 1);
        int y2 = min(max((int)truncf(y2f), 0), HH - 1);
        if ((cf >= 0.3f) && (x2 > x1) && (y2 > y1)) {
            int lo = max(y1, r0);
            int hi = min(y2 - 1, r0 + RSTRIP - 1);
            if (lo <= hi) {
                int xa = x2 - 1;
                int xb = x1 - 1;   // may be -1 -> contributes 0
                for (int r = lo; r <= hi; ++r) {
                    float vv = L[r - r0][xa];
                    if (xb >= 0) vv -= L[r - r0][xb];
                    sum += vv;
                }
            }
        }
        boxacc[(size_t)s * SSTRIDE + b * NN + t] = sum;
    }
}

// Finalize: reduce the 128 per-strip partials per box, then
// relu(sum/area)*conf, mean over B*N. One atomic per block into the
// (pre-zeroed) output.
__global__ __launch_bounds__(256) void finalize_kernel(
    const float4* __restrict__ boxes,
    const float* __restrict__ conf,
    const float* __restrict__ boxacc,
    float* __restrict__ out)
{
    int i = blockIdx.x * 256 + threadIdx.x;
    float local = 0.f;
    if (i < BB * NN) {
        float acc = 0.f;
        #pragma unroll 16
        for (int s = 0; s < NSTRIP; ++s)
            acc += boxacc[(size_t)s * SSTRIDE + i];   // wave-coalesced, stride 9600
        float4 bx = boxes[i];
        float cf  = conf[i];
        float x1f = (bx.x - 0.5f * bx.z) * (float)WW;
        float x2f = (bx.x + 0.5f * bx.z) * (float)WW;
        float y1f = (bx.y - 0.5f * bx.w) * (float)HH;
        float y2f = (bx.y + 0.5f * bx.w) * (float)HH;
        int x1 = min(max((int)truncf(x1f), 0), WW - 1);
        int x2 = min(max((int)truncf(x2f), 0), WW - 1);
        int y1 = min(max((int)truncf(y1f), 0), HH - 1);
        int y2 = min(max((int)truncf(y2f), 0), HH - 1);
        if ((cf >= 0.3f) && (x2 > x1) && (y2 > y1)) {
            float area = (float)((y2 - y1) * (x2 - x1));
            local = fmaxf(acc / area, 0.f) * cf;
        }
    }
    #pragma unroll
    for (int d = 32; d > 0; d >>= 1)
        local += __shfl_down(local, d, 64);
    __shared__ float bsum[4];
    int lane = threadIdx.x & 63, warp = threadIdx.x >> 6;
    if (lane == 0) bsum[warp] = local;
    __syncthreads();
    if (threadIdx.x == 0) {
        float tsum = bsum[0] + bsum[1] + bsum[2] + bsum[3];
        atomicAdd(out, tsum * (1.0f / (BB * NN)));
    }
}

extern "C" void kernel_launch(void* const* d_in, const int* in_sizes, int n_in,
                              void* d_out, int out_size, void* d_ws, size_t ws_size,
                              hipStream_t stream) {
    const float4* boxes = (const float4*)d_in[0];  // (32,300,4)
    const float*  conf  = (const float*)d_in[1];   // (32,300)
    const float*  seg   = (const float*)d_in[2];   // (32,3,1024,1024)
    float* out    = (float*)d_out;
    float* boxacc = (float*)d_ws;                  // 128 * 9600 floats = 4.9 MB

    hipMemsetAsync(out, 0, sizeof(float), stream);
    strip_kernel<<<BB * NSTRIP, 512, 0, stream>>>(seg, boxes, conf, boxacc);
    finalize_kernel<<<(BB * NN + 255) / 256, 256, 0, stream>>>(boxes, conf, boxacc, out);
}